// Round 8
// baseline (18501.289 us; speedup 1.0000x reference)
//
#include <hip/hip_runtime.h>
#include <hip/hip_bf16.h>

// ---------------------------------------------------------------------------
// 3-layer original-paper GRU, B=128, T=128, I=512, H={512,1024,2048}.
// Round 8: diagonal pipeline + split-K GEMM with in-kernel finisher.
//  - Block: M=128 x N=128, BK=64, 4 waves x (64x64 tile, 4x4 16x16x32 mfma).
//    LDS 2x32KB dbuf -> 2 blocks/CU; XOR-swizzled staging via global_load_lds;
//    plain __syncthreads (R6's manual vmcnt pinning regressed; R7's LDS-free
//    FM GEMM was L1-bandwidth-bound -> both abandoned).
//  - Split-K: zr/n L1 layers S=2, L2 S=4 -> serial chains 12-16 chunks (was
//    48). Producers store fp32 partials (col-major f32x4), __threadfence,
//    atomicAdd tile counter; last block sums + bias + activation + writes.
//    Counter condition (old % S == S-1) -> no per-tick zeroing needed.
//  - Diagonal scan as R5: tick u = (layer l, t=u-l), zr+n kernels per tick,
//    h double-buffered by parity, input projection fused in the K-stream.
// Workspace ~86 MB.
// ---------------------------------------------------------------------------

typedef __attribute__((ext_vector_type(8))) short s16x8;
typedef __attribute__((ext_vector_type(4))) float f32x4;

#define LLDS16(g, s)                                                          \
  __builtin_amdgcn_global_load_lds(                                           \
      (const __attribute__((address_space(1))) void*)(g),                     \
      (__attribute__((address_space(3))) void*)(s), 16, 0, 0)

__device__ __forceinline__ unsigned short f2b(float f) {
  unsigned int u = __float_as_uint(f);
  unsigned int r = (u + 0x7FFFu + ((u >> 16) & 1u)) >> 16;
  return (unsigned short)r;
}
__device__ __forceinline__ float sigmoidf_(float x) {
  return 1.0f / (1.0f + __expf(-x));
}
__device__ __forceinline__ float tanhf_(float x) {
  x = fminf(fmaxf(x, -15.0f), 15.0f);
  float e = __expf(-2.0f * x);
  return (1.0f - e) / (1.0f + e);
}

struct DiagP {
  const unsigned short* xb;      // [B,T,I] bf16 row-major
  const unsigned short* wih[3];  // [3H, inl] bf16
  const unsigned short* whh[3];  // [3H, H] bf16
  const float* bias[3];          // [3H]
  float* hf[3][2];               // f32 h by tick parity
  unsigned short* hb[3][2];      // bf16 h by tick parity
  float* zb[3];                  // [128,H] f32 z
  unsigned short* rh[3];         // [128,H] bf16 r*h
  float* partL1;                 // split-K partials (L1 layers)
  float* partL2;                 // split-K partials (L2 layer)
  int* cnt;                      // tile counters (monotonic)
  const float* mask;             // [B,T]
  float* out;                    // [B,3584]
};

// Stage a 128x64 bf16 tile into LDS (16 KB), XOR-swizzled.
// LDS(row, cg) = row*128B + ((cg ^ (row&7))*16B); lds dst = seg*1KB + lane*16B.
__device__ __forceinline__ void stage64(const unsigned short* __restrict__ g,
                                        size_t ld, int rowbase, int k0,
                                        unsigned short* lds) {
  const int tid = threadIdx.x;
  const int wave = tid >> 6, lane = tid & 63;
  const int rl = lane >> 3, cg = lane & 7;
#pragma unroll
  for (int j = 0; j < 4; ++j) {
    int seg = wave * 4 + j;       // 16 segments of 8 rows
    int row = seg * 8 + rl;       // 0..127
    int gc = cg ^ (row & 7);      // swizzled 16B column group
    LLDS16(g + (size_t)(rowbase + row) * ld + k0 + gc * 8, lds + seg * 512);
  }
}

// One BK=64 chunk; wave (wg,wc) computes rows wg*64+[0,64), cols wc*64+[0,64).
__device__ __forceinline__ void cchunk64(const unsigned short* Ab,
                                         const unsigned short* Bb,
                                         f32x4 acc[4][4]) {
  const int tid = threadIdx.x;
  const int wave = tid >> 6, lane = tid & 63;
  const int wg = wave >> 1, wc = wave & 1, quad = lane >> 4, l16 = lane & 15;
#pragma unroll
  for (int ks = 0; ks < 2; ++ks) {
    const int kg = ks * 4 + quad;
    s16x8 av[4], bv[4];
#pragma unroll
    for (int i = 0; i < 4; ++i) {
      int ra = wg * 64 + i * 16 + l16;
      av[i] = *(const s16x8*)(Ab + (size_t)ra * 64 + ((kg ^ (ra & 7)) * 8));
      int rb = wc * 64 + i * 16 + l16;
      bv[i] = *(const s16x8*)(Bb + (size_t)rb * 64 + ((kg ^ (rb & 7)) * 8));
    }
#pragma unroll
    for (int mi = 0; mi < 4; ++mi)
#pragma unroll
      for (int ni = 0; ni < 4; ++ni)
        acc[mi][ni] = __builtin_amdgcn_mfma_f32_16x16x32_bf16(
            av[mi], bv[ni], acc[mi][ni], 0, 0, 0);
  }
}

// acc += chunks [c0,c1) of the fused K-stream A1@B1^T (Cin chunks) then A2@B2^T.
__device__ __forceinline__ void gemmKS(
    const unsigned short* __restrict__ A1, size_t ldA1, int Cin,
    const unsigned short* __restrict__ A2, size_t ldA2,
    const unsigned short* __restrict__ B1, size_t ldB1,
    const unsigned short* __restrict__ B2, size_t ldB2, int brow, int c0,
    int c1, unsigned short* As, unsigned short* Bs, f32x4 acc[4][4]) {
  auto issue = [&](int c, int buf) {
    unsigned short* a = As + buf * 8192;
    unsigned short* b = Bs + buf * 8192;
    if (c < Cin) {
      stage64(A1, ldA1, 0, c << 6, a);
      stage64(B1, ldB1, brow, c << 6, b);
    } else {
      int k0 = (c - Cin) << 6;
      stage64(A2, ldA2, 0, k0, a);
      stage64(B2, ldB2, brow, k0, b);
    }
  };
  issue(c0, 0);
  for (int c = c0; c < c1; ++c) {
    const int idx = c - c0;
    __syncthreads();
    if (c + 1 < c1) issue(c + 1, (idx + 1) & 1);
    cchunk64(As + (idx & 1) * 8192, Bs + (idx & 1) * 8192, acc);
  }
}

// ---- zr: z/r gates. 168 blocks: L0 8 (S=1), L1 16x2, L2 32x4. ----
__global__ __launch_bounds__(256) void diag_zr(DiagP p, int u) {
  __shared__ unsigned short As[2 * 8192], Bs[2 * 8192];
  const int blk = blockIdx.x;
  int l, nt, s, S;
  if (blk < 8) {
    l = 0; nt = blk; s = 0; S = 1;
  } else if (blk < 40) {
    int r = blk - 8; l = 1; nt = r >> 1; s = r & 1; S = 2;
  } else {
    int r = blk - 40; l = 2; nt = r >> 2; s = r & 3; S = 4;
  }
  const int t = u - l;
  if (t < 0 || t >= 128) return;
  const int H = 512 << l, inl = (l == 0) ? 512 : (512 << (l - 1));
  const int oldS = (u + 1) & 1;
  const unsigned short* A1 =
      (l == 0) ? p.xb + (size_t)t * 512 : p.hb[l - 1][oldS];
  const size_t ldA1 = (l == 0) ? (size_t)65536 : (size_t)inl;
  const int Cin = inl >> 6, total = Cin + (H >> 6);
  const int c0 = s * total / S, c1 = (s + 1) * total / S;

  f32x4 acc[4][4] = {};
  gemmKS(A1, ldA1, Cin, p.hb[l][oldS], (size_t)H, p.wih[l], (size_t)inl,
         p.whh[l], (size_t)H, nt * 128, c0, c1, As, Bs, acc);

  const int tid = threadIdx.x, wave = tid >> 6, lane = tid & 63;
  const int wg = wave >> 1, wc = wave & 1, quad = lane >> 4, l16 = lane & 15;
  float* part = nullptr;
  const int stride = 2 * H;
  if (S > 1) {
    part = (l == 1) ? p.partL1 : p.partL2;
#pragma unroll
    for (int ni = 0; ni < 4; ++ni) {
      int colg = nt * 128 + wc * 64 + ni * 16 + l16;
#pragma unroll
      for (int mi = 0; mi < 4; ++mi) {
        int rowb = wg * 64 + mi * 16 + quad * 4;
        *(f32x4*)(part + ((size_t)(s * stride + colg) * 128 + rowb)) =
            acc[mi][ni];
      }
    }
    __threadfence();
    __syncthreads();
    __shared__ int oldv;
    if (tid == 0) oldv = atomicAdd(&p.cnt[(l == 1) ? nt : 16 + nt], 1);
    __syncthreads();
    if ((oldv % S) != S - 1) return;  // not the finisher
    __threadfence();
  }
  const float* hfo = p.hf[l][oldS];
#pragma unroll
  for (int ni = 0; ni < 4; ++ni) {
    const int colg = nt * 128 + wc * 64 + ni * 16 + l16;
    const float bv = p.bias[l][colg];
    const bool isz = colg < H;  // uniform per tile (128 | H)
    const int j = isz ? colg : colg - H;
#pragma unroll
    for (int mi = 0; mi < 4; ++mi) {
      const int rowb = wg * 64 + mi * 16 + quad * 4;
      f32x4 v;
      if (S == 1) {
        v = acc[mi][ni];
      } else {
        v = *(const f32x4*)(part + ((size_t)colg * 128 + rowb));
        for (int s2 = 1; s2 < S; ++s2)
          v += *(const f32x4*)(part +
                               ((size_t)(s2 * stride + colg) * 128 + rowb));
      }
#pragma unroll
      for (int r = 0; r < 4; ++r) {
        const int row = rowb + r;
        const float sg = sigmoidf_(v[r] + bv);
        if (isz)
          p.zb[l][(size_t)row * H + j] = sg;
        else
          p.rh[l][(size_t)row * H + j] = f2b(sg * hfo[(size_t)row * H + j]);
      }
    }
  }
}

// ---- n: n gate + h update + out. 84 blocks: L0 4 (S=1), L1 8x2, L2 16x4. ----
__global__ __launch_bounds__(256) void diag_n(DiagP p, int u) {
  __shared__ unsigned short As[2 * 8192], Bs[2 * 8192];
  const int blk = blockIdx.x;
  int l, nt, s, S;
  if (blk < 4) {
    l = 0; nt = blk; s = 0; S = 1;
  } else if (blk < 20) {
    int r = blk - 4; l = 1; nt = r >> 1; s = r & 1; S = 2;
  } else {
    int r = blk - 20; l = 2; nt = r >> 2; s = r & 3; S = 4;
  }
  const int t = u - l;
  if (t < 0 || t >= 128) return;
  const int H = 512 << l, inl = (l == 0) ? 512 : (512 << (l - 1));
  const int outoff = (l == 0) ? 0 : ((l == 1) ? 512 : 1536);
  const int oldS = (u + 1) & 1, newS = u & 1;
  const unsigned short* A1 =
      (l == 0) ? p.xb + (size_t)t * 512 : p.hb[l - 1][oldS];
  const size_t ldA1 = (l == 0) ? (size_t)65536 : (size_t)inl;
  const int Cin = inl >> 6, total = Cin + (H >> 6);
  const int c0 = s * total / S, c1 = (s + 1) * total / S;

  f32x4 acc[4][4] = {};
  gemmKS(A1, ldA1, Cin, p.rh[l], (size_t)H, p.wih[l] + (size_t)2 * H * inl,
         (size_t)inl, p.whh[l] + (size_t)2 * H * H, (size_t)H, nt * 128, c0,
         c1, As, Bs, acc);

  const int tid = threadIdx.x, wave = tid >> 6, lane = tid & 63;
  const int wg = wave >> 1, wc = wave & 1, quad = lane >> 4, l16 = lane & 15;
  float* part = nullptr;
  const int stride = H;
  if (S > 1) {
    part = (l == 1) ? p.partL1 : p.partL2;
#pragma unroll
    for (int ni = 0; ni < 4; ++ni) {
      int colg = nt * 128 + wc * 64 + ni * 16 + l16;
#pragma unroll
      for (int mi = 0; mi < 4; ++mi) {
        int rowb = wg * 64 + mi * 16 + quad * 4;
        *(f32x4*)(part + ((size_t)(s * stride + colg) * 128 + rowb)) =
            acc[mi][ni];
      }
    }
    __threadfence();
    __syncthreads();
    __shared__ int oldv;
    if (tid == 0) oldv = atomicAdd(&p.cnt[(l == 1) ? 48 + nt : 56 + nt], 1);
    __syncthreads();
    if ((oldv % S) != S - 1) return;
    __threadfence();
  }
  const float* hfo = p.hf[l][oldS];
  float* hfn = p.hf[l][newS];
  unsigned short* hbn = p.hb[l][newS];
#pragma unroll
  for (int ni = 0; ni < 4; ++ni) {
    const int colg = nt * 128 + wc * 64 + ni * 16 + l16;
    const float bv = p.bias[l][2 * H + colg];
#pragma unroll
    for (int mi = 0; mi < 4; ++mi) {
      const int rowb = wg * 64 + mi * 16 + quad * 4;
      f32x4 v;
      if (S == 1) {
        v = acc[mi][ni];
      } else {
        v = *(const f32x4*)(part + ((size_t)colg * 128 + rowb));
        for (int s2 = 1; s2 < S; ++s2)
          v += *(const f32x4*)(part +
                               ((size_t)(s2 * stride + colg) * 128 + rowb));
      }
#pragma unroll
      for (int r = 0; r < 4; ++r) {
        const int row = rowb + r;
        const float nv = tanhf_(v[r] + bv);
        const size_t idx = (size_t)row * H + colg;
        const float z = p.zb[l][idx];
        const float hn = (1.0f - z) * nv + z * hfo[idx];
        hfn[idx] = hn;
        hbn[idx] = f2b(hn);
        p.out[(size_t)row * 3584 + outoff + colg] +=
            p.mask[row * 128 + t] * hn;
      }
    }
  }
}

__global__ void cast_kernel(const float* __restrict__ src,
                            unsigned short* __restrict__ dst, int n) {
  int i = blockIdx.x * 256 + threadIdx.x;
  if (i < n) dst[i] = f2b(src[i]);
}

extern "C" void kernel_launch(void* const* d_in, const int* in_sizes, int n_in,
                              void* d_out, int out_size, void* d_ws,
                              size_t ws_size, hipStream_t stream) {
  const int B = 128, T = 128, I = 512;
  const int Hs[3] = {512, 1024, 2048};

  const float* x = (const float*)d_in[0];
  const float* mask = (const float*)d_in[1];
  const float* Wih[3] = {(const float*)d_in[2], (const float*)d_in[5],
                         (const float*)d_in[8]};
  const float* Whh[3] = {(const float*)d_in[3], (const float*)d_in[6],
                         (const float*)d_in[9]};
  const float* bias[3] = {(const float*)d_in[4], (const float*)d_in[7],
                          (const float*)d_in[10]};

  char* ws = (char*)d_ws;
  size_t off = 0;
  auto alloc = [&](size_t bytes) -> void* {
    void* p = ws + off;
    off = (off + bytes + 255) & ~(size_t)255;
    return p;
  };

  DiagP p;
  unsigned short* xb = (unsigned short*)alloc((size_t)B * T * I * 2);
  unsigned short *wihb[3], *whhb[3];
  for (int l = 0; l < 3; ++l) {
    int inl = (l == 0) ? I : Hs[l - 1];
    wihb[l] = (unsigned short*)alloc((size_t)3 * Hs[l] * inl * 2);
    whhb[l] = (unsigned short*)alloc((size_t)3 * Hs[l] * Hs[l] * 2);
  }
  size_t hstart = off;
  for (int l = 0; l < 3; ++l)
    for (int sl = 0; sl < 2; ++sl)
      p.hf[l][sl] = (float*)alloc((size_t)B * Hs[l] * 4);
  for (int l = 0; l < 3; ++l)
    for (int sl = 0; sl < 2; ++sl)
      p.hb[l][sl] = (unsigned short*)alloc((size_t)B * Hs[l] * 2);
  p.cnt = (int*)alloc(256 * 4);
  size_t hend = off;  // memset covers h state + counters
  for (int l = 0; l < 3; ++l) p.zb[l] = (float*)alloc((size_t)B * Hs[l] * 4);
  for (int l = 0; l < 3; ++l)
    p.rh[l] = (unsigned short*)alloc((size_t)B * Hs[l] * 2);
  p.partL1 = (float*)alloc((size_t)2 * 128 * 4096 * 4);  // 4 MB (zr-L1 needs 2x2048)
  p.partL2 = (float*)alloc((size_t)4 * 128 * 4096 * 4);  // 8 MB
  (void)ws_size;

  p.xb = xb;
  for (int l = 0; l < 3; ++l) {
    p.wih[l] = wihb[l];
    p.whh[l] = whhb[l];
    p.bias[l] = bias[l];
  }
  p.mask = mask;
  p.out = (float*)d_out;

  auto cast = [&](const float* s, unsigned short* d, int n) {
    cast_kernel<<<(n + 255) / 256, 256, 0, stream>>>(s, d, n);
  };
  cast(x, xb, B * T * I);
  for (int l = 0; l < 3; ++l) {
    int inl = (l == 0) ? I : Hs[l - 1];
    cast(Wih[l], wihb[l], 3 * Hs[l] * inl);
    cast(Whh[l], whhb[l], 3 * Hs[l] * Hs[l]);
  }
  hipMemsetAsync(ws + hstart, 0, hend - hstart, stream);
  hipMemsetAsync(d_out, 0, (size_t)out_size * 4, stream);

  // ---- diagonal scan: tick u covers (l, t=u-l) ----
  for (int u = 0; u < T + 2; ++u) {
    diag_zr<<<168, 256, 0, stream>>>(p, u);
    diag_n<<<84, 256, 0, stream>>>(p, u);
  }
}